// Round 8
// baseline (132.218 us; speedup 1.0000x reference)
//
#include <hip/hip_runtime.h>
#include <hip/hip_bf16.h>

#define BATCH   32
#define TLEN    128000
#define FGAIN   1000
#define ORDER   26
#define WLEN    512
#define HOP     128
#define PAD     192                 // (512-128)/2
#define TPAD    (TLEN + 2*PAD)      // 128384 padded length
#define NFRAME  1000
#define NTOT    (BATCH*NFRAME)      // 32000 frames total

#define CHUNK   64                  // frames per k_lpc block (= 1 wave)
#define NCHUNK  ((NFRAME + CHUNK - 1) / CHUNK)   // 16 (15 full + tail of 40)
#define XS_SPAN (CHUNK*HOP + WLEN - HOP)         // 8576 floats staged per block
#define XS_LDS  8656                // 8576 + 67 pad + slack
#define GS_LDS  80                  // 72 gain taps needed, padded
#define YSTRIDE 53                  // 52 cols + 1 pad (odd -> 2 lanes/bank)

// ---------------------------------------------------------------------------
// Kernel A: fused (gain-upsample x ex) staging + per-frame order-26 IIR.
// One frame per lane, one wave per block, 64 consecutive frames per block.
//
// R2: scattered-VMEM-bound. R3: float4 superblocks. R5: LDS x-staging
// (neutral at dur level -> stores suspected dominant). R6 (this):
//  (a) exg computed inline during staging (k_exg kernel deleted),
//  (b) fw stores transposed through ys[64][53] LDS tile: 16 rows per store
//      instruction (1 cache line per row) -> 16 lines/instr vs 64.
// Tap 0 applied LAST so the cross-step critical path is a single FMA.
// ---------------------------------------------------------------------------
__global__ __launch_bounds__(64) void k_lpc(const float* __restrict__ ex,
                                            const float* __restrict__ gain,
                                            const float* __restrict__ acoef,
                                            float* __restrict__ fw) {
  __shared__ float xs[XS_LDS];
  __shared__ float gs[GS_LDS];
  __shared__ float ys[CHUNK * YSTRIDE];       // 64x53 = 3392 floats

  const int lane = threadIdx.x;               // 0..63
  const int n0   = blockIdx.x * CHUNK;        // first frame of this chunk
  const int b    = blockIdx.y;                // batch row
  const float* __restrict__ exr = ex + (size_t)b * TLEN;
  const float* __restrict__ gr  = gain + b * FGAIN;

  // ---- stage gain taps: i0 range for this chunk is [n0-2, n0+67] ----
  const int GBASE = n0 - 2;
  for (int i = lane; i < 72; i += 64) {
    int gidx = GBASE + i;
    gidx = gidx < 0 ? 0 : (gidx > FGAIN - 1 ? FGAIN - 1 : gidx);
    gs[i] = gr[gidx];
  }
  __syncthreads();

  // ---- stage x = ex * upsample(gain) into LDS, padded-zero outside ----
  // padded position g = n0*128 + s; ex index j = g - PAD. j%4==0 -> the
  // float4 is all-in or all-out of [0, TLEN).
  for (int i = lane; i < XS_SPAN / 4; i += 64) {
    int s = 4 * i;
    int j = n0 * HOP + s - PAD;
    float vv[4] = {0.f, 0.f, 0.f, 0.f};
    if (j >= 0 && j < TLEN) {
      float4 e = *reinterpret_cast<const float4*>(exr + j);
      float ee[4] = {e.x, e.y, e.z, e.w};
#pragma unroll
      for (int c = 0; c < 4; ++c) {
        // mirrors JAX: src = clip((j+0.5)/128 - 0.5, 0, 999); exact in f32
        float src = ((float)(j + c) + 0.5f) * (1.0f / (float)HOP) - 0.5f;
        src = fminf(fmaxf(src, 0.0f), (float)(FGAIN - 1));
        int   i0 = (int)src;                  // floor (src >= 0)
        float w  = src - (float)i0;
        int   i1 = i0 + 1; if (i1 > FGAIN - 1) i1 = FGAIN - 1;
        float g  = gs[i0 - GBASE] * (1.0f - w) + gs[i1 - GBASE] * w;
        vv[c] = ee[c] * g;
      }
    }
    int base = s + (s >> 7);                  // +1 pad per 128 floats
    xs[base + 0] = vv[0];  xs[base + 1] = vv[1];
    xs[base + 2] = vv[2];  xs[base + 3] = vv[3];
  }
  __syncthreads();

  // ---- per-lane frame setup ----
  int f = b * NFRAME + n0 + lane;
  int f_cl = f < NTOT ? f : NTOT - 1;         // clamp for tail-chunk dummies
  const float* __restrict__ ap = acoef + (size_t)f_cl * ORDER;
  const size_t fwrow0 = (size_t)(b * NFRAME + n0) * WLEN;  // row base for stores

  float a[ORDER], h[ORDER];
#pragma unroll
  for (int q = 0; q < 13; ++q) {              // 13 x float2 (8B-aligned base)
    float2 v = *reinterpret_cast<const float2*>(ap + 2 * q);
    a[2 * q] = v.x;  a[2 * q + 1] = v.y;
  }
#pragma unroll
  for (int k = 0; k < ORDER; ++k) h[k] = 0.0f;

  float buf[52];                               // x for the current superblock

  // Invariant at step s (t % 26 == 0): h[m] holds the newest y at time
  // congruent to m (mod 26). Need y[t+s-1-k] -> slot ((s-1-k) mod 26).
  // y goes to the ys transpose tile (banks (21*lane+s)%32 -> 2/bank, free).
#define LPC_STEP(s) {                                                      \
    float xv = buf[(s)];                                                   \
    float p0 = xv, p1 = 0.f, p2 = 0.f, p3 = 0.f;                           \
    _Pragma("unroll")                                                      \
    for (int k = 1; k < ORDER; ++k) {                                      \
      float hv = h[((s) - 1 - k + 2 * ORDER) % ORDER];                     \
      int sel = k & 3;                                                     \
      if      (sel == 0) p0 -= a[k] * hv;                                  \
      else if (sel == 1) p1 -= a[k] * hv;                                  \
      else if (sel == 2) p2 -= a[k] * hv;                                  \
      else               p3 -= a[k] * hv;                                  \
    }                                                                      \
    float rest = (p0 + p1) + (p2 + p3);                                    \
    float y = rest - a[0] * h[((s) + ORDER - 1) % ORDER];                  \
    h[(s) % ORDER] = y;                                                    \
    ys[lane * YSTRIDE + (s)] = y;                                          \
  }

  // lane's frame occupies LDS positions lane*128 + u -> padded lane*129+u+(u>>7)
#define LOAD_BUF(nq) {                                                     \
    _Pragma("unroll")                                                      \
    for (int q = 0; q < (nq); ++q) {                                       \
      int u = t + 4 * q;                                                   \
      int base = lane * 129 + u + (u >> 7);                                \
      buf[4 * q + 0] = xs[base + 0];                                       \
      buf[4 * q + 1] = xs[base + 1];                                       \
      buf[4 * q + 2] = xs[base + 2];                                       \
      buf[4 * q + 3] = xs[base + 3];                                       \
    }                                                                      \
  }

  // Transposed store: lane -> (row r = rr*16 + lane>>2, float4-col q = (lane&3)+4*jj).
  // 16 rows x 64 contiguous bytes per instruction = 16 cache lines (vs 64).
#define STORE_YS(nq) {                                                     \
    __syncthreads();                                                       \
    _Pragma("unroll")                                                      \
    for (int jj = 0; jj < 4; ++jj) {                                       \
      int q = (lane & 3) + 4 * jj;                                         \
      if (q < (nq)) {                                                      \
        _Pragma("unroll")                                                  \
        for (int rr = 0; rr < 4; ++rr) {                                   \
          int r = rr * 16 + (lane >> 2);                                   \
          if ((n0 + r) < NFRAME) {                                         \
            float4 vv = make_float4(ys[r * YSTRIDE + 4 * q + 0],           \
                                    ys[r * YSTRIDE + 4 * q + 1],           \
                                    ys[r * YSTRIDE + 4 * q + 2],           \
                                    ys[r * YSTRIDE + 4 * q + 3]);          \
            *reinterpret_cast<float4*>(fw + fwrow0 + (size_t)r * WLEN      \
                                       + t + 4 * q) = vv;                  \
          }                                                                \
        }                                                                  \
      }                                                                    \
    }                                                                      \
    __syncthreads();                                                       \
  }

  int t = 0;
  for (int sb = 0; sb < 9; ++sb) {            // 9 * 52 = 468
    LOAD_BUF(13)
#pragma unroll
    for (int s = 0; s < 52; ++s) {
      LPC_STEP(s)
    }
    STORE_YS(13)
    t += 52;
  }
  // epilogue: t = 468 (468 % 26 == 0), 44 remaining steps = 11 x float4
  LOAD_BUF(11)
#pragma unroll
  for (int s = 0; s < 44; ++s) {
    LPC_STEP(s)
  }
  STORE_YS(11)
#undef LPC_STEP
#undef LOAD_BUF
#undef STORE_YS
}

// ---------------------------------------------------------------------------
// Kernel B: windowed overlap-add + normalization.
// out[b][j] = ( sum_n fw[b][n][p-128n] * win[p-128n] ) / ( sum_n win[p-128n] ),
// p = j + PAD. 4 outputs per thread; w0 is always a multiple of 4 so every
// frame covers all-4-or-none samples and all float4 accesses are 16B-aligned.
// Each fw element is read exactly once globally -> traffic floor ~81 MB.
// ---------------------------------------------------------------------------
__global__ __launch_bounds__(256) void k_ola(const float* __restrict__ fw,
                                             const float* __restrict__ win,
                                             float* __restrict__ out) {
  int gid = blockIdx.x * 256 + threadIdx.x;   // one thread per 4 outputs
  const int total4 = BATCH * TLEN / 4;
  if (gid >= total4) return;
  int idx = gid * 4;
  int b  = idx / TLEN;
  int j0 = idx - b * TLEN;
  int p0 = j0 + PAD;

  // frames n with 0 <= p0-128n <= 508:  ceil((p0-508)/128) == (p0-381)/128
  int lo = (p0 - 381) / HOP;
  if (lo < 0) lo = 0;
  int hi = p0 / HOP;
  if (hi > NFRAME - 1) hi = NFRAME - 1;

  float ax = 0.f, ay = 0.f, az = 0.f, aw = 0.f;
  float nx = 0.f, ny = 0.f, nz = 0.f, nw = 0.f;
  for (int n = lo; n <= hi; ++n) {
    int w0 = p0 - n * HOP;       // 0..508, multiple of 4
    const float4 fv = *reinterpret_cast<const float4*>(fw + ((size_t)b * NFRAME + n) * WLEN + w0);
    const float4 wv = *reinterpret_cast<const float4*>(win + w0);
    ax += fv.x * wv.x;  ay += fv.y * wv.y;  az += fv.z * wv.z;  aw += fv.w * wv.w;
    nx += wv.x;         ny += wv.y;         nz += wv.z;         nw += wv.w;
  }
  float4 o = make_float4(ax / nx, ay / ny, az / nz, aw / nw);
  *reinterpret_cast<float4*>(out + idx) = o;
}

// ---------------------------------------------------------------------------
extern "C" void kernel_launch(void* const* d_in, const int* in_sizes, int n_in,
                              void* d_out, int out_size, void* d_ws, size_t ws_size,
                              hipStream_t stream) {
  const float* ex   = (const float*)d_in[0];   // [32][128000]
  const float* gain = (const float*)d_in[1];   // [32][1000]
  const float* a    = (const float*)d_in[2];   // [32][1000][26]
  const float* win  = (const float*)d_in[3];   // [512]
  // d_in[4] = hop_length (=128, compile-time constant here)
  float* outp = (float*)d_out;                 // [32][128000]

  // workspace layout: fw [32][1000][512] f32 = 65.5 MB (exg buffer deleted)
  float* fw = (float*)d_ws;

  {
    hipLaunchKernelGGL(k_lpc, dim3(NCHUNK, BATCH), dim3(64), 0, stream,
                       ex, gain, a, fw);
  }
  {
    int total4 = BATCH * TLEN / 4;
    int blocks = (total4 + 255) / 256;
    hipLaunchKernelGGL(k_ola, dim3(blocks), dim3(256), 0, stream, fw, win, outp);
  }
}

// Round 10
// 127.729 us; speedup vs baseline: 1.0351x; 1.0351x over previous
//
#include <hip/hip_runtime.h>
#include <hip/hip_bf16.h>

#define BATCH   32
#define TLEN    128000
#define FGAIN   1000
#define ORDER   26
#define WLEN    512
#define HOP     128
#define PAD     192                 // (512-128)/2
#define TPAD    (TLEN + 2*PAD)      // 128384 padded length
#define NFRAME  1000
#define NTOT    (BATCH*NFRAME)      // 32000 frames total

#define CHUNK   64                  // frames per k_lpc block (= 1 wave)
#define NCHUNK  ((NFRAME + CHUNK - 1) / CHUNK)   // 16 (15 full + tail of 40)
#define XS_SPAN (CHUNK*HOP + WLEN - HOP)         // 8576 floats staged per block
#define XS_LDS  8656                // 8576 + 67 pad + slack
#define GS_LDS  80                  // 72 gain taps needed, padded
#define YSTRIDE 53                  // 52 cols + 1 pad (odd -> 2 lanes/bank)

// Single-wave workgroup: cross-lane LDS visibility in the MAIN LOOP needs only
// a DS-queue drain, not a barrier; crucially this never drains vmcnt, so the
// scattered fw stores stay fire-and-forget. (R9's failure was a macro
// shadowing bug in staging, not this fence — see STAGE_COMPUTE sc_* rename.)
#define WAVE_LDS_FENCE() asm volatile("s_waitcnt lgkmcnt(0)" ::: "memory")

// ---------------------------------------------------------------------------
// Kernel A: fused (gain-upsample x ex) staging + per-frame order-26 IIR.
// One frame per lane, one wave per block, 64 consecutive frames per block.
//
// R8 measured (barrier version): 56us, VALUBusy 17%, Occ 4.5% -> latency-
// stalled at 0.5 waves/SIMD (no TLP). R10 (this):
//  (a) 8-deep pipelined staging loads (was ~34 serial ~900cy HBM latencies),
//  (b) staging syncs = __syncthreads (cheap there); main-loop syncs = DS
//      fence only (no vmcnt(0) store drains, ~20x),
//  (c) coefs staged coalesced through LDS (was 64-way scattered float2s),
//  (d) R9 bugfix: STAGE_COMPUTE internals renamed sc_* -- the tail calls
//      passed a variable named i_ into a macro that declared int i_ = (i_);
//      (self-initialization -> garbage LDS offsets -> absmax 317).
// ---------------------------------------------------------------------------
__global__ __launch_bounds__(64) void k_lpc(const float* __restrict__ ex,
                                            const float* __restrict__ gain,
                                            const float* __restrict__ acoef,
                                            float* __restrict__ fw) {
  __shared__ float xs[XS_LDS];
  __shared__ float gs[GS_LDS];
  __shared__ float as_lin[CHUNK * ORDER];     // 1664 floats, coalesced-staged
  __shared__ float ys[CHUNK * YSTRIDE];       // 64x53 transpose tile

  const int lane = threadIdx.x;               // 0..63
  const int n0   = blockIdx.x * CHUNK;        // first frame of this chunk
  const int b    = blockIdx.y;                // batch row
  const float* __restrict__ exr = ex + (size_t)b * TLEN;
  const float* __restrict__ gr  = gain + b * FGAIN;

  // ---- stage gain taps: i0 range for this chunk is [n0-2, n0+66] ----
  const int GBASE = n0 - 2;
  for (int i = lane; i < 72; i += 64) {
    int gidx = GBASE + i;
    gidx = gidx < 0 ? 0 : (gidx > FGAIN - 1 ? FGAIN - 1 : gidx);
    gs[i] = gr[gidx];
  }
  __syncthreads();                            // gs visible (cheap: no stores yet)

  // ---- stage coefs coalesced: 416 float4 = frames [n0, n0+64) ----
  {
    const int e0_4 = (b * NFRAME + n0) * ORDER / 4;    // divisible: n0%64==0
    const int lim4 = NTOT * ORDER / 4;                 // 208000
    for (int v = lane; v < CHUNK * ORDER / 4; v += 64) {
      float4 c = make_float4(0.f, 0.f, 0.f, 0.f);
      if (e0_4 + v < lim4)
        c = *reinterpret_cast<const float4*>(acoef + 4 * (size_t)(e0_4 + v));
      *reinterpret_cast<float4*>(as_lin + 4 * v) = c;
    }
  }

  // ---- stage x = ex * upsample(gain), 8-deep pipelined loads ----
  // element group index i in [0, XS_SPAN/4): span offset sc_s = 4*i,
  // ex index sc_j = n0*128 + sc_s - PAD. All macro locals are sc_-prefixed;
  // callers must not pass variables named sc_* (R9 lesson).
  const int sbase = n0 * HOP;
#define STAGE_COMPUTE(IDX4, EVAL) {                                        \
    int sc_s = 4 * (IDX4);                                                 \
    int sc_j = sbase + sc_s - PAD;                                         \
    float sc_v[4] = {0.f, 0.f, 0.f, 0.f};                                  \
    if (sc_j >= 0 && sc_j <= TLEN - 4) {                                   \
      float sc_e[4] = {(EVAL).x, (EVAL).y, (EVAL).z, (EVAL).w};            \
      _Pragma("unroll")                                                    \
      for (int sc_c = 0; sc_c < 4; ++sc_c) {                               \
        float sc_src = ((float)(sc_j + sc_c) + 0.5f) * (1.0f / (float)HOP) \
                       - 0.5f;                                             \
        sc_src = fminf(fmaxf(sc_src, 0.0f), (float)(FGAIN - 1));           \
        int   sc_i0 = (int)sc_src;                                         \
        float sc_w  = sc_src - (float)sc_i0;                               \
        int   sc_i1 = sc_i0 + 1; if (sc_i1 > FGAIN - 1) sc_i1 = FGAIN - 1; \
        float sc_g  = gs[sc_i0 - GBASE] * (1.0f - sc_w)                    \
                    + gs[sc_i1 - GBASE] * sc_w;                            \
        sc_v[sc_c] = sc_e[sc_c] * sc_g;                                    \
      }                                                                    \
    }                                                                      \
    int sc_b = sc_s + (sc_s >> 7);            /* +1 pad per 128 floats */  \
    xs[sc_b + 0] = sc_v[0];  xs[sc_b + 1] = sc_v[1];                       \
    xs[sc_b + 2] = sc_v[2];  xs[sc_b + 3] = sc_v[3];                       \
  }
  for (int g8 = 0; g8 < 4; ++g8) {            // 32 full iterations, 8-deep
    float4 ev[8];
#pragma unroll
    for (int u = 0; u < 8; ++u) {             // issue 8 independent loads
      int gi = lane + 64 * (8 * g8 + u);
      int gj = sbase + 4 * gi - PAD;
      ev[u] = make_float4(0.f, 0.f, 0.f, 0.f);
      if (gj >= 0 && gj <= TLEN - 4)
        ev[u] = *reinterpret_cast<const float4*>(exr + gj);
    }
#pragma unroll
    for (int u = 0; u < 8; ++u) {             // then consume
      STAGE_COMPUTE(lane + 64 * (8 * g8 + u), ev[u])
    }
  }
  {                                           // it = 32 (full)
    int ti = lane + 2048;
    int tj = sbase + 4 * ti - PAD;
    float4 te = make_float4(0.f, 0.f, 0.f, 0.f);
    if (tj >= 0 && tj <= TLEN - 4)
      te = *reinterpret_cast<const float4*>(exr + tj);
    STAGE_COMPUTE(ti, te)
  }
  if (lane < XS_SPAN / 4 - 2112) {            // it = 33 (partial: lane < 32)
    int ti = lane + 2112;
    int tj = sbase + 4 * ti - PAD;
    float4 te = make_float4(0.f, 0.f, 0.f, 0.f);
    if (tj >= 0 && tj <= TLEN - 4)
      te = *reinterpret_cast<const float4*>(exr + tj);
    STAGE_COMPUTE(ti, te)
  }
#undef STAGE_COMPUTE
  __syncthreads();                            // xs + as_lin visible
                                              // (staging loads already waited,
                                              //  so the vmcnt drain is ~free)

  // ---- per-lane frame setup (coefs from LDS, ds_read_b64) ----
  float a[ORDER], h[ORDER];
  {
    const float* __restrict__ al = as_lin + lane * ORDER;  // 8B-aligned
#pragma unroll
    for (int q = 0; q < 13; ++q) {
      float2 v = *reinterpret_cast<const float2*>(al + 2 * q);
      a[2 * q] = v.x;  a[2 * q + 1] = v.y;
    }
  }
#pragma unroll
  for (int k = 0; k < ORDER; ++k) h[k] = 0.0f;

  const size_t fwrow0 = (size_t)(b * NFRAME + n0) * WLEN;
  float buf[52];

  // Invariant at step s (t % 26 == 0): h[m] holds the newest y at time
  // congruent to m (mod 26). Need y[t+s-1-k] -> slot ((s-1-k) mod 26).
#define LPC_STEP(s) {                                                      \
    float xv = buf[(s)];                                                   \
    float p0 = xv, p1 = 0.f, p2 = 0.f, p3 = 0.f;                           \
    _Pragma("unroll")                                                      \
    for (int k = 1; k < ORDER; ++k) {                                      \
      float hv = h[((s) - 1 - k + 2 * ORDER) % ORDER];                     \
      int sel = k & 3;                                                     \
      if      (sel == 0) p0 -= a[k] * hv;                                  \
      else if (sel == 1) p1 -= a[k] * hv;                                  \
      else if (sel == 2) p2 -= a[k] * hv;                                  \
      else               p3 -= a[k] * hv;                                  \
    }                                                                      \
    float rest = (p0 + p1) + (p2 + p3);                                    \
    float y = rest - a[0] * h[((s) + ORDER - 1) % ORDER];                  \
    h[(s) % ORDER] = y;                                                    \
    ys[lane * YSTRIDE + (s)] = y;                                          \
  }

#define LOAD_BUF(nq) {                                                     \
    _Pragma("unroll")                                                      \
    for (int q = 0; q < (nq); ++q) {                                       \
      int u = t + 4 * q;                                                   \
      int base = lane * 129 + u + (u >> 7);                                \
      buf[4 * q + 0] = xs[base + 0];                                       \
      buf[4 * q + 1] = xs[base + 1];                                       \
      buf[4 * q + 2] = xs[base + 2];                                       \
      buf[4 * q + 3] = xs[base + 3];                                       \
    }                                                                      \
  }

  // Transposed store: 16 rows x 64B contiguous per instr = 16 lines vs 64.
  // DS fences (not barriers) around it: vmcnt never drained in-loop.
#define STORE_YS(nq) {                                                     \
    WAVE_LDS_FENCE();          /* ys writes visible before cross-lane read */\
    _Pragma("unroll")                                                      \
    for (int jj = 0; jj < 4; ++jj) {                                       \
      int q = (lane & 3) + 4 * jj;                                         \
      if (q < (nq)) {                                                      \
        _Pragma("unroll")                                                  \
        for (int rr = 0; rr < 4; ++rr) {                                   \
          int r = rr * 16 + (lane >> 2);                                   \
          if ((n0 + r) < NFRAME) {                                         \
            float4 vv = make_float4(ys[r * YSTRIDE + 4 * q + 0],           \
                                    ys[r * YSTRIDE + 4 * q + 1],           \
                                    ys[r * YSTRIDE + 4 * q + 2],           \
                                    ys[r * YSTRIDE + 4 * q + 3]);          \
            *reinterpret_cast<float4*>(fw + fwrow0 + (size_t)r * WLEN      \
                                       + t + 4 * q) = vv;                  \
          }                                                                \
        }                                                                  \
      }                                                                    \
    }                                                                      \
    WAVE_LDS_FENCE();          /* reads done before next superblock WAR */ \
  }

  int t = 0;
  for (int sb = 0; sb < 9; ++sb) {            // 9 * 52 = 468
    LOAD_BUF(13)
#pragma unroll
    for (int s = 0; s < 52; ++s) {
      LPC_STEP(s)
    }
    STORE_YS(13)
    t += 52;
  }
  // epilogue: t = 468 (468 % 26 == 0), 44 remaining steps = 11 x float4
  LOAD_BUF(11)
#pragma unroll
  for (int s = 0; s < 44; ++s) {
    LPC_STEP(s)
  }
  STORE_YS(11)
#undef LPC_STEP
#undef LOAD_BUF
#undef STORE_YS
}

// ---------------------------------------------------------------------------
// Kernel B: windowed overlap-add + normalization.
// out[b][j] = ( sum_n fw[b][n][p-128n] * win[p-128n] ) / ( sum_n win[p-128n] ),
// p = j + PAD. 4 outputs per thread; w0 is always a multiple of 4 so every
// frame covers all-4-or-none samples and all float4 accesses are 16B-aligned.
// ---------------------------------------------------------------------------
__global__ __launch_bounds__(256) void k_ola(const float* __restrict__ fw,
                                             const float* __restrict__ win,
                                             float* __restrict__ out) {
  int gid = blockIdx.x * 256 + threadIdx.x;   // one thread per 4 outputs
  const int total4 = BATCH * TLEN / 4;
  if (gid >= total4) return;
  int idx = gid * 4;
  int b  = idx / TLEN;
  int j0 = idx - b * TLEN;
  int p0 = j0 + PAD;

  // frames n with 0 <= p0-128n <= 508:  ceil((p0-508)/128) == (p0-381)/128
  int lo = (p0 - 381) / HOP;
  if (lo < 0) lo = 0;
  int hi = p0 / HOP;
  if (hi > NFRAME - 1) hi = NFRAME - 1;

  float ax = 0.f, ay = 0.f, az = 0.f, aw = 0.f;
  float nx = 0.f, ny = 0.f, nz = 0.f, nw = 0.f;
  for (int n = lo; n <= hi; ++n) {
    int w0 = p0 - n * HOP;       // 0..508, multiple of 4
    const float4 fv = *reinterpret_cast<const float4*>(fw + ((size_t)b * NFRAME + n) * WLEN + w0);
    const float4 wv = *reinterpret_cast<const float4*>(win + w0);
    ax += fv.x * wv.x;  ay += fv.y * wv.y;  az += fv.z * wv.z;  aw += fv.w * wv.w;
    nx += wv.x;         ny += wv.y;         nz += wv.z;         nw += wv.w;
  }
  float4 o = make_float4(ax / nx, ay / ny, az / nz, aw / nw);
  *reinterpret_cast<float4*>(out + idx) = o;
}

// ---------------------------------------------------------------------------
extern "C" void kernel_launch(void* const* d_in, const int* in_sizes, int n_in,
                              void* d_out, int out_size, void* d_ws, size_t ws_size,
                              hipStream_t stream) {
  const float* ex   = (const float*)d_in[0];   // [32][128000]
  const float* gain = (const float*)d_in[1];   // [32][1000]
  const float* a    = (const float*)d_in[2];   // [32][1000][26]
  const float* win  = (const float*)d_in[3];   // [512]
  // d_in[4] = hop_length (=128, compile-time constant here)
  float* outp = (float*)d_out;                 // [32][128000]

  // workspace layout: fw [32][1000][512] f32 = 65.5 MB
  float* fw = (float*)d_ws;

  {
    hipLaunchKernelGGL(k_lpc, dim3(NCHUNK, BATCH), dim3(64), 0, stream,
                       ex, gain, a, fw);
  }
  {
    int total4 = BATCH * TLEN / 4;
    int blocks = (total4 + 255) / 256;
    hipLaunchKernelGGL(k_ola, dim3(blocks), dim3(256), 0, stream, fw, win, outp);
  }
}